// Round 1
// baseline (84.807 us; speedup 1.0000x reference)
//
#include <hip/hip_runtime.h>

// ---------------------------------------------------------------------------
// HybridNN, fully fused single kernel — direct per-sample circuit evaluation.
//
// R(prev): 2-D table + bilinear lookup measured 77 us. rocprof showed the
// harness's 256 MB d_ws poison fill alone is ~41.5 us (HBM-roofline, not
// ours); the remaining ~32 us was our two kernels. eval_kernel's 4 random
// dword gathers/sample over a 64 KB table generate ~3.6M divergent L1/L2
// line-transactions (~55 distinct lines per wave gather) -> L2 request-
// throughput bound, ~25-30 us.
//
// This version: no table, no gathers, no d_ws. The 8 Rot matrices (sample-
// independent) are built once per block in LDS by threads 0-7, broadcast-
// copied to registers, and the full 4-layer 2-qubit circuit (~455 VALU ops +
// ~14 transcendentals per sample) is evaluated in registers per sample.
// 1024 blocks x 256 threads x 4 samples/thread = 16 waves/CU, compute-bound
// at ~7-8 us. Also removes the bilinear interpolation error (absmax was
// sitting at 3.9e-3).
// ---------------------------------------------------------------------------

typedef float vfloat4 __attribute__((ext_vector_type(4)));

struct c2 { float re, im; };

__device__ __forceinline__ c2 cmul(c2 a, c2 b) {
    c2 r;
    r.re = fmaf(a.re, b.re, -(a.im * b.im));
    r.im = fmaf(a.re, b.im, a.im * b.re);
    return r;
}

__device__ __forceinline__ c2 cfma(c2 a, c2 b, c2 acc) {
    acc.re = fmaf(a.re, b.re, fmaf(-a.im, b.im, acc.re));
    acc.im = fmaf(a.re, b.im, fmaf(a.im, b.re, acc.im));
    return acc;
}

__device__ __forceinline__ void rx_pair(c2& u, c2& v, float c, float s) {
    c2 nu, nv;
    nu.re = fmaf(c, u.re,  s * v.im);
    nu.im = fmaf(c, u.im, -(s * v.re));
    nv.re = fmaf(c, v.re,  s * u.im);
    nv.im = fmaf(c, v.im, -(s * u.re));
    u = nu; v = nv;
}

__device__ __forceinline__ void rot_pair(c2& u, c2& v, c2 g00, c2 g01, c2 g10, c2 g11) {
    c2 nu = cmul(g00, u); nu = cfma(g01, v, nu);
    c2 nv = cmul(g10, u); nv = cfma(g11, v, nv);
    u = nu; v = nv;
}

__device__ __forceinline__ float ftanh(float v) {
    float e = __expf(2.0f * v);
    return __fdividef(e - 1.0f, e + 1.0f);
}

// Full circuit + post-net for one sample. Rs must be static-indexable
// (register array after inlining; all loops unrolled).
__device__ __forceinline__ float circuit_y(float g0, float g1,
                                           const float (*Rs)[2][8],
                                           float pw0, float pw1, float pb) {
    float cs0, sn0, cs1, sn1;
    __sincosf(0.5f * g0, &sn0, &cs0);
    __sincosf(0.5f * g1, &sn1, &cs1);

    c2 s00 = {1.0f, 0.0f}, s01 = {0.0f, 0.0f};
    c2 s10 = {0.0f, 0.0f}, s11 = {0.0f, 0.0f};

#pragma unroll
    for (int l = 0; l < 4; l++) {
        // AngleEmbedding: RX(g0) on wire0, RX(g1) on wire1
        rx_pair(s00, s10, cs0, sn0);
        rx_pair(s01, s11, cs0, sn0);
        rx_pair(s00, s01, cs1, sn1);
        rx_pair(s10, s11, cs1, sn1);
        // Rot on wire0
        {
            const float* r = Rs[l][0];
            c2 g00 = {r[0], r[1]}, g01 = {r[2], r[3]};
            c2 g10 = {r[4], r[5]}, g11 = {r[6], r[7]};
            rot_pair(s00, s10, g00, g01, g10, g11);
            rot_pair(s01, s11, g00, g01, g10, g11);
        }
        // Rot on wire1
        {
            const float* r = Rs[l][1];
            c2 g00 = {r[0], r[1]}, g01 = {r[2], r[3]};
            c2 g10 = {r[4], r[5]}, g11 = {r[6], r[7]};
            rot_pair(s00, s01, g00, g01, g10, g11);
            rot_pair(s10, s11, g00, g01, g10, g11);
        }
        { c2 tmp = s10; s10 = s11; s11 = tmp; }  // CNOT(0,1)
        { c2 tmp = s01; s01 = s11; s11 = tmp; }  // CNOT(1,0)
    }

    float p00 = fmaf(s00.re, s00.re, s00.im * s00.im);
    float p01 = fmaf(s01.re, s01.re, s01.im * s01.im);
    float p10 = fmaf(s10.re, s10.re, s10.im * s10.im);
    float p11 = fmaf(s11.re, s11.re, s11.im * s11.im);
    float z0 = (p00 + p01) - (p10 + p11);
    float z1 = (p00 + p10) - (p01 + p11);

    float q0 = 0.5f * (z0 + 1.0f);
    float q1 = 0.5f * (z1 + 1.0f);
    float y  = fmaf(pw0, q0, fmaf(pw1, q1, pb));
    return __fdividef(1.0f, 1.0f + __expf(-y));
}

__global__ __launch_bounds__(256) void fused_eval(
    const float* __restrict__ x,       // (B,2)
    const float* __restrict__ pre_w1,  // (4,2)
    const float* __restrict__ pre_b1,  // (4,)
    const float* __restrict__ pre_w2,  // (2,4)
    const float* __restrict__ pre_b2,  // (2,)
    const float* __restrict__ qw,      // (4,2,3)
    const float* __restrict__ post_w,  // (1,2)
    const float* __restrict__ post_b,  // (1,)
    float* __restrict__ out,           // (B,)
    int nbatch)
{
    // --- build the 8 sample-independent Rot matrices once per block ---
    __shared__ __align__(16) float Rs_lds[4][2][8];
    int tid = threadIdx.x;
    if (tid < 8) {
        int l = tid >> 1, w = tid & 1;
        const float* p = qw + (l * 2 + w) * 3;
        float phi = p[0], th = p[1], om = p[2];
        float c  = cosf(0.5f * th), s = sinf(0.5f * th);
        float a  = 0.5f * (phi + om), b = 0.5f * (phi - om);
        float ca = cosf(a), sa = sinf(a);
        float cb = cosf(b), sb = sinf(b);
        float* r = Rs_lds[l][w];
        r[0] =  c * ca;  r[1] = -c * sa;   // g00
        r[2] = -s * cb;  r[3] = -s * sb;   // g01
        r[4] =  s * cb;  r[5] = -s * sb;   // g10
        r[6] =  c * ca;  r[7] =  c * sa;   // g11 = conj(g00)
    }
    __syncthreads();

    // broadcast-copy Rot matrices LDS -> registers (same address across all
    // lanes: conflict-free; 16x ds_read_b128, once per thread lifetime)
    float R[4][2][8];
    {
        const vfloat4* src = reinterpret_cast<const vfloat4*>(&Rs_lds[0][0][0]);
        vfloat4* dst = reinterpret_cast<vfloat4*>(&R[0][0][0]);
#pragma unroll
        for (int i = 0; i < 16; i++) dst[i] = src[i];
    }

    float w1[8], b1[4], w2[8], b2[2];
#pragma unroll
    for (int i = 0; i < 8; i++) w1[i] = pre_w1[i];
#pragma unroll
    for (int i = 0; i < 4; i++) b1[i] = pre_b1[i];
#pragma unroll
    for (int i = 0; i < 8; i++) w2[i] = pre_w2[i];
#pragma unroll
    for (int i = 0; i < 2; i++) b2[i] = pre_b2[i];
    float pw0 = post_w[0], pw1 = post_w[1], pb = post_b[0];

    int base = (blockIdx.x * blockDim.x + tid) * 4;
    if (base >= nbatch) return;

    if (base + 4 <= nbatch) {
        // fast path: full quad, vectorized I/O
        float4 xa = *reinterpret_cast<const float4*>(x + 2 * (long long)base);
        float4 xb = *reinterpret_cast<const float4*>(x + 2 * (long long)base + 4);
        float xs0[4] = { xa.x, xa.z, xb.x, xb.z };
        float xs1[4] = { xa.y, xa.w, xb.y, xb.w };
        float res[4];

#pragma unroll
        for (int t = 0; t < 4; t++) {
            float x0 = xs0[t], x1 = xs1[t];

            float h0 = ftanh(fmaf(w1[0], x0, fmaf(w1[1], x1, b1[0])));
            float h1 = ftanh(fmaf(w1[2], x0, fmaf(w1[3], x1, b1[1])));
            float h2 = ftanh(fmaf(w1[4], x0, fmaf(w1[5], x1, b1[2])));
            float h3 = ftanh(fmaf(w1[6], x0, fmaf(w1[7], x1, b1[3])));

            float u0 = fmaf(w2[0], h0, fmaf(w2[1], h1, fmaf(w2[2], h2, fmaf(w2[3], h3, b2[0]))));
            float u1 = fmaf(w2[4], h0, fmaf(w2[5], h1, fmaf(w2[6], h2, fmaf(w2[7], h3, b2[1]))));

            res[t] = circuit_y(ftanh(u0), ftanh(u1), R, pw0, pw1, pb);
        }

        vfloat4 r4 = { res[0], res[1], res[2], res[3] };
        __builtin_nontemporal_store(r4, reinterpret_cast<vfloat4*>(out + base));
    } else {
        // tail (never taken for B = 2^20, kept for generality)
        for (int t = 0; t < 4; t++) {
            int idx = base + t;
            if (idx >= nbatch) break;
            float x0 = x[2 * (long long)idx];
            float x1 = x[2 * (long long)idx + 1];

            float h0 = ftanh(fmaf(w1[0], x0, fmaf(w1[1], x1, b1[0])));
            float h1 = ftanh(fmaf(w1[2], x0, fmaf(w1[3], x1, b1[1])));
            float h2 = ftanh(fmaf(w1[4], x0, fmaf(w1[5], x1, b1[2])));
            float h3 = ftanh(fmaf(w1[6], x0, fmaf(w1[7], x1, b1[3])));

            float u0 = fmaf(w2[0], h0, fmaf(w2[1], h1, fmaf(w2[2], h2, fmaf(w2[3], h3, b2[0]))));
            float u1 = fmaf(w2[4], h0, fmaf(w2[5], h1, fmaf(w2[6], h2, fmaf(w2[7], h3, b2[1]))));

            out[idx] = circuit_y(ftanh(u0), ftanh(u1), R, pw0, pw1, pb);
        }
    }
}

extern "C" void kernel_launch(void* const* d_in, const int* in_sizes, int n_in,
                              void* d_out, int out_size, void* d_ws, size_t ws_size,
                              hipStream_t stream) {
    const float* x      = (const float*)d_in[0];
    const float* pre_w1 = (const float*)d_in[1];
    const float* pre_b1 = (const float*)d_in[2];
    const float* pre_w2 = (const float*)d_in[3];
    const float* pre_b2 = (const float*)d_in[4];
    const float* qw     = (const float*)d_in[5];
    const float* post_w = (const float*)d_in[6];
    const float* post_b = (const float*)d_in[7];
    float* out = (float*)d_out;
    (void)d_ws; (void)ws_size;  // workspace unused — no table, no gathers

    int nbatch  = in_sizes[0] / 2;
    int threads = 256;
    int spb     = threads * 4;                    // 4 samples/thread
    int blocks  = (nbatch + spb - 1) / spb;       // 1024 blocks @ B=2^20
    hipLaunchKernelGGL(fused_eval, dim3(blocks), dim3(threads), 0, stream,
                       x, pre_w1, pre_b1, pre_w2, pre_b2, qw, post_w, post_b,
                       out, nbatch);
}